// Round 4
// baseline (19223.801 us; speedup 1.0000x reference)
//
#include <hip/hip_runtime.h>
#include <hip/hip_bf16.h>

typedef __hip_bfloat16 bf16;
typedef _Float16 f16;
typedef _Float16 f16x8 __attribute__((ext_vector_type(8)));
typedef float f32x4 __attribute__((ext_vector_type(4)));
typedef unsigned long long u64;
typedef unsigned short ushort_t;

__device__ __forceinline__ float b2f(bf16 x){ return __bfloat162float(x); }
__device__ __forceinline__ float sigf(float x){ return 1.f/(1.f+expf(-x)); }
__device__ __forceinline__ float splus(float x){ return fmaxf(x,0.f)+log1pf(expf(-fabsf(x))); }
__device__ __forceinline__ float ldf(const void* p, int i, int isf32){
  return isf32 ? ((const float*)p)[i] : __bfloat162float(((const bf16*)p)[i]);
}
// agent-scope coherent ops (bypass per-XCD L2). Proven cross-XCD coherent, no fences.
__device__ __forceinline__ void ast64(u64* p, u64 v){ __hip_atomic_store(p, v, __ATOMIC_RELAXED, __HIP_MEMORY_SCOPE_AGENT); }
__device__ __forceinline__ u64 ald64(u64* p){ return __hip_atomic_load(p, __ATOMIC_RELAXED, __HIP_MEMORY_SCOPE_AGENT); }
__device__ __forceinline__ void ast32(unsigned* p, unsigned v){ __hip_atomic_store(p, v, __ATOMIC_RELAXED, __HIP_MEMORY_SCOPE_AGENT); }
__device__ __forceinline__ unsigned ald32(unsigned* p){ return __hip_atomic_load(p, __ATOMIC_RELAXED, __HIP_MEMORY_SCOPE_AGENT); }

union U4H8 { uint4 u; f16x8 h; };
union U64H4 { u64 u; f16 h[4]; };
union H16 { f16 h; ushort_t s; };

// ---------------- dtype detect ----------------
__global__ void k_detect(const void* __restrict__ emb, int* __restrict__ flag){
  __shared__ float mx[256];
  int tid=threadIdx.x;
  float v = fabsf(__bfloat162float(((const bf16*)emb)[tid]));
  mx[tid]=v; __syncthreads();
  for(int s=128;s>0;s>>=1){ if(tid<s) mx[tid]=fmaxf(mx[tid],mx[tid+s]); __syncthreads(); }
  if(tid==0){ flag[0] = (mx[0]>1000.f) ? 1 : 0; flag[1] = 0; }
}

// ---------------- setup ----------------
// embW[row][v] = b0[row] + sum_k emb[v][k]*Wi0[row][k]   (row-major [2048][256])
__global__ void k_embW(const void* __restrict__ emb, const void* __restrict__ Wi0,
                       const void* __restrict__ b0,
                       const int* __restrict__ flags, float* __restrict__ embW){
  int f=flags[0];
  int row = blockIdx.x;
  __shared__ float w[512];
  for(int k=threadIdx.x;k<512;k+=256) w[k]=ldf(Wi0,row*576+k,f);
  __syncthreads();
  int v = threadIdx.x;
  float acc=ldf(b0,row,f);
  #pragma unroll 4
  for(int k=0;k<512;k++) acc += ldf(emb,v*512+k,f)*w[k];
  embW[row*256+v]=acc;
}

// ---- weight prepack (group design) ----
// Block (g,r): r owns hidden dims [32r,32r+32) -> 128 gate rows. Wave w=G*2+h owns
// rows G*512 + r*32 + h*16 + [0,16). A-frag 16x16x32 f16: lane l row (l&15),
// k=(l>>4)*8+j.  PA chunks c=0..17: k<512 Wh0, k>=512 Wi0 lr cols.
__global__ void k_wpkA(const void* __restrict__ Wh0, const void* __restrict__ Wi0,
                       const int* __restrict__ flags, ushort_t* __restrict__ PA){
  int f=flags[0];
  int idx=blockIdx.x*256+threadIdx.x;
  if(idx>=1179648) return;
  int j=idx&7, l=(idx>>3)&63, rest=idx>>9;
  int c=rest%18, t2=rest/18, w=t2&7, r=t2>>3;
  int G=w>>1, hh=w&1, m=l&15, q4=l>>4;
  int row=G*512 + r*32 + hh*16 + m;
  int k=c*32 + q4*8 + j;
  float val = (k<512)? ldf(Wh0,row*512+k,f) : ldf(Wi0,row*576+k,f);
  H16 hx; hx.h=(f16)val; PA[idx]=hx.s;
}
// PB chunks c=0..31: k<512 Wi1 (h0(t)), k>=512 Wh1 (h1(t-1)).
__global__ void k_wpkB(const void* __restrict__ Wi1, const void* __restrict__ Wh1,
                       const int* __restrict__ flags, ushort_t* __restrict__ PB){
  int f=flags[0];
  int idx=blockIdx.x*256+threadIdx.x;
  if(idx>=2097152) return;
  int j=idx&7, l=(idx>>3)&63, rest=idx>>9;
  int c=rest&31, t2=rest>>5, w=t2&7, r=t2>>3;
  int G=w>>1, hh=w&1, m=l&15, q4=l>>4;
  int row=G*512 + r*32 + hh*16 + m;
  int k=c*32 + q4*8 + j;
  float val = (k<512)? ldf(Wi1,row*512+k,f) : ldf(Wh1,row*512+k-512,f);
  H16 hx; hx.h=(f16)val; PB[idx]=hx.s;
}

// W_ifT [512][136] (col 135 pad, unused). Also zeroes the compact flag array FL
// (4 groups x 16 dwords, one 64B line per group).
__global__ void k_wifT(const void* __restrict__ W_if, const void* __restrict__ b_if,
                       const int* __restrict__ flags,
                       float* __restrict__ W_ifT, float* __restrict__ b_ifF,
                       unsigned* __restrict__ FLz){
  int f=flags[0];
  int idx=blockIdx.x*256+threadIdx.x;
  if(idx<135*512){ int v=idx/512, k=idx-v*512; W_ifT[k*136+v]=ldf(W_if,idx,f); }
  if(idx<64) FLz[idx]=0u;
  if(idx<135) b_ifF[idx]=ldf(b_if,idx,f);
}

__global__ void k_wc(const void* __restrict__ W_fc, const void* __restrict__ W_out,
                     const void* __restrict__ b_out, const void* __restrict__ b_fc,
                     const int* __restrict__ flags,
                     float* __restrict__ Wc, float* __restrict__ bc){
  int f=flags[0];
  int idx=blockIdx.x*256+threadIdx.x;
  int v=idx/576, j=idx-v*576;
  float acc=0.f;
  #pragma unroll 4
  for(int d=0;d<512;d++) acc += ldf(W_fc,v*512+d,f)*ldf(W_out,d*576+j,f);
  Wc[idx]=acc;
  if(j==0){
    float a=ldf(b_fc,v,f);
    for(int d=0;d<512;d++) a += ldf(W_fc,v*512+d,f)*ldf(b_out,d,f);
    bc[v]=a;
  }
}

// ---------------- grouped recurrence, hop-covered rotation ----------------
// 4 independent groups x 16 blocks; block (g,r) owns dims [32r,32r+32), weights
// truly register-resident (waves_per_eu(2,2) -> 256-VGPR budget; 1 block/CU).
// Flags: FL[g*16+r], one 64B line per group. alpha(t)=3t+2 beta(t)=3t+3 gamma(t)=3t+4.
// Rotated schedule per iteration tt (covers beta & gamma hops):
//   cover1 = A(tt+1)p1: 16 MFMA on h0(tt) ALREADY IN LDS (staged by B p2; layout identical)
//   wait beta(tt) -> P3(tt) -> publish gamma(tt)
//   cover2 = B(tt+1)p1: stage h1(tt) + 16 MFMA (+ cat stores)
//   wait gamma(tt) -> A p2 (lr chunk, nonlin) -> publish alpha(tt+1)
//   wait alpha(tt+1) [exposed hop] -> B p2 (stage h0(tt+1), 16 MFMA, nonlin) -> publish beta(tt+1)
// Overwrite safety: every phase-buffer overwrite is flag-chain-ordered >= 1 full
// iteration after all readers of the old contents (re-verified for GX0/GX1/GXL).
__attribute__((amdgpu_waves_per_eu(2,2)))
__global__ void __launch_bounds__(512) k_dnc3(
    const int* __restrict__ tokens, const void* __restrict__ b1, const int* __restrict__ flags,
    const float* __restrict__ embW, const ushort_t* __restrict__ PA, const ushort_t* __restrict__ PB,
    const float* __restrict__ W_ifT, const float* __restrict__ b_ifF,
    u64* GX0, u64* GX1, u64* GXL, unsigned* FL,
    bf16* __restrict__ cat)
{
  const int bid = blockIdx.x;
  const int g   = bid>>4, r = bid&15;
  const int tid = threadIdx.x;
  const int wv  = tid>>6, l = tid&63;
  const int lm  = l&15,  q4 = l>>4;
  const int d   = tid>>4, bb = tid&15;     // (dim, batch) for nonlinearity
  const int f32i = flags[0];

  __shared__ __align__(16) u64 HB[4352];   // [0..2047] h0 | [2048..4095] h1prev | [4096..4351] lr
  __shared__ float PR[128*17];
  __shared__ f16  sh_pub[512];
  __shared__ float sh_b1[128];
  __shared__ float oc[512];
  __shared__ float xis[136], xpart[3*136];
  __shared__ float s_mem[80], s_mem2[80], s_link[25], s_link2[25];
  __shared__ float s_prec[5], s_prec2[5], s_rwp[20], s_rw[20];
  __shared__ float s_wwp[5], s_ww[5], s_usage[5], s_wl[5];
  __shared__ float s_rl[20], s_fwd[20], s_bwd[20], s_wsum;
  __shared__ float rvbuf[64];

#define WAITG(TGT) do{ if(tid<16){ unsigned _tg=(unsigned)(TGT); int _wd=0; \
    while(ald32(&FL[g*16+tid]) < _tg && _wd<50000000){ __builtin_amdgcn_s_sleep(1); _wd++; } } \
  __syncthreads(); }while(0)
#define PUBF(VAL) do{ __syncthreads(); \
  if(tid==0) ast32(&FL[g*16+r],(unsigned)(VAL)); }while(0)

  // resident weight fragments (200 VGPR) — waves_per_eu(2,2) gives the budget
  f16x8 fa[18], fb[32];
  {
    const uint4* PAv=(const uint4*)PA;
    const uint4* PBv=(const uint4*)PB;
    #pragma unroll
    for(int c=0;c<18;c++){ U4H8 t4; t4.u = PAv[((r*8+wv)*18+c)*64 + l]; fa[c]=t4.h; }
    #pragma unroll
    for(int c=0;c<32;c++){ U4H8 t4; t4.u = PBv[((r*8+wv)*32+c)*64 + l]; fb[c]=t4.h; }
    #pragma unroll
    for(int c=0;c<18;c++) asm volatile("" :: "v"(fa[c]));
    #pragma unroll
    for(int c=0;c<32;c++) asm volatile("" :: "v"(fb[c]));
  }
  if(tid<128) sh_b1[tid]=ldf(b1,(tid>>5)*512 + r*32 + (tid&31), f32i);
  if(tid<80) s_mem[tid]=0.f;
  if(tid>=128&&tid<153) s_link[tid-128]=0.f;
  if(tid>=160&&tid<165) s_prec[tid-160]=0.f;
  if(tid>=192&&tid<212) s_rwp[tid-192]=0.f;
  if(tid>=224&&tid<229) s_wwp[tid-224]=0.f;
  if(tid>=256&&tid<261) s_usage[tid-256]=0.f;
  float c0s=0.f, c1s=0.f;

  const f16x8* HBv=(const f16x8*)HB;

  // ---- prologue: t=0 (no stale-buffer reads anywhere) ----
  {
    // h0(0) = nonlin(em(0)) — recurrent and lr terms are zero
    int tok0=tokens[(g*16+bb)*512];
    int base0=(r*32+d)*256+tok0;
    float e0=embW[base0], e1=embW[131072+base0], e2=embW[262144+base0], e3=embW[393216+base0];
    (void)e1;
    c0s = sigf(e0)*tanhf(e2);
    float h0v = sigf(e3)*tanhf(c0s);
    sh_pub[d*16+bb]=(f16)h0v;
  }
  __syncthreads();
  if(tid<128){
    int ks=tid>>4, b2=tid&15;
    U64H4 pk;
    #pragma unroll
    for(int i=0;i<4;i++) pk.h[i]=sh_pub[(ks*4+i)*16+b2];
    ast64(&GX0[g*4096+0*2048+((4*r+(ks>>1))*16+b2)*2+(ks&1)], pk.u);
  }
  PUBF(2u);            // alpha(0)
  WAITG(2u);
  {
    u64 s0=ald64(&GX0[g*4096+tid      ]);
    u64 s1=ald64(&GX0[g*4096+tid+512  ]);
    u64 s2=ald64(&GX0[g*4096+tid+1024 ]);
    u64 s3=ald64(&GX0[g*4096+tid+1536 ]);
    HB[tid]=s0; HB[tid+512]=s1; HB[tid+1024]=s2; HB[tid+1536]=s3;
  }
  __syncthreads();
  {
    f32x4 accB=(f32x4){0.f,0.f,0.f,0.f};
    #pragma unroll
    for(int c=0;c<16;c++){
      f16x8 bfr=HBv[(c*4+q4)*16+lm];
      accB=__builtin_amdgcn_mfma_f32_16x16x32_f16(fb[c],bfr,accB,0,0,0);
    }
    #pragma unroll
    for(int reg=0;reg<4;reg++) PR[(wv*16+q4*4+reg)*17+lm]=accB[reg];
  }
  __syncthreads();
  {
    float gi=PR[(d    )*17+bb]+sh_b1[d];
    float gf=PR[(32+d )*17+bb]+sh_b1[32+d]; (void)gf;
    float gg=PR[(64+d )*17+bb]+sh_b1[64+d];
    float go=PR[(96+d )*17+bb]+sh_b1[96+d];
    c1s = sigf(gi)*tanhf(gg);            // c1 prev = 0
    float h=sigf(go)*tanhf(c1s);
    sh_pub[d*16+bb]=(f16)h;
  }
  __syncthreads();
  if(tid<128){
    int ks=tid>>4, b2=tid&15;
    U64H4 pk;
    #pragma unroll
    for(int i=0;i<4;i++) pk.h[i]=sh_pub[(ks*4+i)*16+b2];
    ast64(&GX1[g*4096+0*2048+((4*r+(ks>>1))*16+b2)*2+(ks&1)], pk.u);
  }
  PUBF(3u);            // beta(0)

  // ---- main rotated loop ----
  for(int tt=0;tt<512;tt++){
    const int p=tt&1, pn=p^1;

    // cover1: A(tt+1) p1 on h0(tt) resident in HB[0..2047]
    f32x4 accA=(f32x4){0.f,0.f,0.f,0.f};
    #pragma unroll
    for(int c=0;c<16;c++){
      f16x8 bfr=HBv[(c*4+q4)*16+lm];
      accA=__builtin_amdgcn_mfma_f32_16x16x32_f16(fa[c],bfr,accA,0,0,0);
    }
    // prefetch em(tt+1)
    float em0,em1,em2,em3;
    {
      int tn = (tt<511)? tt+1 : 511;
      int tok=tokens[(g*16+bb)*512+tn];
      int base=(r*32+d)*256+tok;
      em0=embW[base]; em1=embW[131072+base]; em2=embW[262144+base]; em3=embW[393216+base];
    }

    WAITG(3*tt+3);     // beta(tt)

    // ====== P3(tt) for batch g*16+r ======
    if(tid<128){
      int kg2=tid>>1, e2=tid&1;
      U64H4 pv; pv.u=ald64(&GX1[g*4096+p*2048+(kg2*16+r)*2+e2]);
      #pragma unroll
      for(int jj=0;jj<4;jj++){
        float x=(float)pv.h[jj];
        x=fminf(fmaxf(x,-20.f),20.f);
        oc[kg2*8+e2*4+jj]=x;
      }
    }
    __syncthreads();
    if(tid<405){
      int qq=tid/135, v=tid-qq*135;
      int k0=qq*171, k1=k0+171; if(k1>512)k1=512;
      float a=0.f;
      for(int k=k0;k<k1;k++) a += oc[k]*W_ifT[k*136+v];
      xpart[qq*136+v]=a;
    }
    __syncthreads();
    if(tid<135) xis[tid]=b_ifF[tid]+xpart[tid]+xpart[136+tid]+xpart[272+tid];
    __syncthreads();
    if(tid<5){
      int m=tid;
      float u=s_usage[m]+(1.f-s_usage[m])*s_wwp[m];
      float psi=1.f;
      #pragma unroll
      for(int rr=0;rr<4;rr++) psi *= 1.f - sigf(xis[117+rr])*s_rwp[rr*5+m];
      u*=psi; s_usage[m]=u;
      float nm=0.f,dt=0.f,nk=0.f;
      #pragma unroll
      for(int w=0;w<16;w++){
        float mv=s_mem[m*16+w], kv=tanhf(xis[68+w]);
        nm+=mv*mv; dt+=mv*kv; nk+=kv*kv;
      }
      float sim=dt/((sqrtf(nm)+1e-6f)*(sqrtf(nk)+1e-6f));
      s_wl[m]=sim*splus(xis[84]);
    }
    __syncthreads();
    if(tid==0){
      float mx=-1e30f;
      for(int m=0;m<5;m++) mx=fmaxf(mx,s_wl[m]);
      float e[5]; float s=0.f;
      for(int m=0;m<5;m++){ e[m]=expf(s_wl[m]-mx); s+=e[m]; }
      float u[5]; int id[5];
      for(int m=0;m<5;m++){ u[m]=1e-6f+(1.f-1e-6f)*s_usage[m]; id[m]=m; }
      for(int i=1;i<5;i++){
        float uv=u[i]; int iv=id[i]; int j=i-1;
        while(j>=0&&u[j]>uv){u[j+1]=u[j];id[j+1]=id[j];j--;}
        u[j+1]=uv; id[j+1]=iv;
      }
      float alm[5]; float prod=1.f;
      for(int i=0;i<5;i++){ alm[id[i]]=(1.f-u[i])*prod; prod*=u[i]; }
      float ag=sigf(xis[121]), wgg=sigf(xis[122]);
      float wsum=0.f;
      for(int m=0;m<5;m++){
        float wcw=e[m]/s;
        float w_=wgg*(ag*alm[m]+(1.f-ag)*wcw);
        s_ww[m]=w_; wsum+=w_;
      }
      s_wsum=wsum;
    }
    __syncthreads();
    if(tid<80){
      int m=tid>>4,w=tid&15;
      float er=sigf(xis[85+w]), wvv=tanhf(xis[101+w]);
      float w_=s_ww[m];
      s_mem2[tid]=s_mem[tid]*(1.f-w_*er)+w_*wvv;
    } else if(tid>=128&&tid<153){
      int qq=tid-128; int i=qq/5, j=qq-5*i;
      s_link2[qq]=(i==j)?0.f:((1.f-s_ww[i]-s_ww[j])*s_link[qq]+s_ww[i]*s_prec[j]);
    } else if(tid>=160&&tid<165){
      int j=tid-160;
      s_prec2[j]=(1.f-s_wsum)*s_prec[j]+s_ww[j];
    }
    __syncthreads();
    if(tid<20){
      int rr=tid/5,m=tid-5*(tid/5);
      float nm=0.f,dt=0.f,nk=0.f;
      #pragma unroll
      for(int w=0;w<16;w++){
        float mv=s_mem2[m*16+w], kv=tanhf(xis[rr*16+w]);
        nm+=mv*mv; dt+=mv*kv; nk+=kv*kv;
      }
      float sim=dt/((sqrtf(nm)+1e-6f)*(sqrtf(nk)+1e-6f));
      s_rl[tid]=sim*splus(xis[64+rr]);
    } else if(tid>=64&&tid<84){
      int qq=tid-64; int rr=qq/5, i=qq-5*rr;
      float a=0.f;
      #pragma unroll
      for(int j=0;j<5;j++) a+=s_link2[i*5+j]*s_rwp[rr*5+j];
      s_fwd[rr*5+i]=a;
    } else if(tid>=96&&tid<116){
      int qq=tid-96; int rr=qq/5, j=qq-5*rr;
      float a=0.f;
      #pragma unroll
      for(int i=0;i<5;i++) a+=s_link2[i*5+j]*s_rwp[rr*5+i];
      s_bwd[rr*5+j]=a;
    }
    __syncthreads();
    if(tid<20){
      int rr=tid/5;
      float mx=-1e30f;
      for(int m=0;m<5;m++) mx=fmaxf(mx,s_rl[rr*5+m]);
      float s=0.f;
      for(int m=0;m<5;m++) s+=expf(s_rl[rr*5+m]-mx);
      float rcw=expf(s_rl[tid]-mx)/s;
      float q0=xis[123+3*rr],q1=xis[124+3*rr],q2=xis[125+3*rr];
      float m3=fmaxf(q0,fmaxf(q1,q2));
      float e0=expf(q0-m3),e1=expf(q1-m3),e2=expf(q2-m3);
      float inv=1.f/(e0+e1+e2);
      s_rw[tid]=(e0*s_bwd[tid]+e1*s_fwd[tid]+e2*rcw)*inv;
    }
    __syncthreads();
    if(tid<64){
      int rr=tid>>4,w=tid&15;
      float a=0.f;
      #pragma unroll
      for(int m=0;m<5;m++) a+=s_rw[rr*5+m]*s_mem2[m*16+w];
      rvbuf[tid]=a;
    } else if(tid>=128&&tid<208){ s_mem [tid-128]=s_mem2 [tid-128];
    } else if(tid>=208&&tid<233){ s_link[tid-208]=s_link2[tid-208];
    } else if(tid>=240&&tid<245){ s_prec[tid-240]=s_prec2[tid-240];
    } else if(tid>=256&&tid<276){ s_rwp [tid-256]=s_rw   [tid-256];
    } else if(tid>=288&&tid<293){ s_wwp [tid-288]=s_ww   [tid-288]; }
    __syncthreads();

    if(tt==511){
      int cb=((g*16+r)*512+tt)*576;
      cat[cb+tid]=__float2bfloat16(oc[tid]);
      if(tid<64) cat[cb+512+tid]=__float2bfloat16(rvbuf[tid]);
      break;
    }

    if(tid<16){
      U64H4 pk;
      #pragma unroll
      for(int i=0;i<4;i++) pk.h[i]=(f16)rvbuf[4*tid+i];
      ast64(&GXL[g*512+p*256+((tid>>1)*16+r)*2+(tid&1)], pk.u);
    }
    PUBF(3*tt+4);      // gamma(tt)

    // cover2: B(tt+1) p1 — stage h1(tt), MFMA; plus cat stores for tt
    {
      u64 s0=ald64(&GX1[g*4096+p*2048+tid      ]);
      u64 s1=ald64(&GX1[g*4096+p*2048+tid+512  ]);
      u64 s2=ald64(&GX1[g*4096+p*2048+tid+1024 ]);
      u64 s3=ald64(&GX1[g*4096+p*2048+tid+1536 ]);
      HB[2048+tid]=s0; HB[2048+tid+512]=s1; HB[2048+tid+1024]=s2; HB[2048+tid+1536]=s3;
    }
    {
      int cb=((g*16+r)*512+tt)*576;
      cat[cb+tid]=__float2bfloat16(oc[tid]);
      if(tid<64) cat[cb+512+tid]=__float2bfloat16(rvbuf[tid]);
    }
    __syncthreads();
    f32x4 accB=(f32x4){0.f,0.f,0.f,0.f};
    #pragma unroll
    for(int c=16;c<32;c++){
      f16x8 bfr=HBv[1024+((c-16)*4+q4)*16+lm];
      accB=__builtin_amdgcn_mfma_f32_16x16x32_f16(fb[c],bfr,accB,0,0,0);
    }

    WAITG(3*tt+4);     // gamma(tt)

    // A(tt+1) p2: lr chunk + nonlinearity
    if(tid<256) HB[4096+tid]=ald64(&GXL[g*512+p*256+tid]);
    __syncthreads();
    #pragma unroll
    for(int cc=0;cc<2;cc++){
      f16x8 bfr=HBv[2048+(cc*4+q4)*16+lm];
      accA=__builtin_amdgcn_mfma_f32_16x16x32_f16(fa[16+cc],bfr,accA,0,0,0);
    }
    #pragma unroll
    for(int reg=0;reg<4;reg++) PR[(wv*16+q4*4+reg)*17+lm]=accA[reg];
    __syncthreads();
    {
      float gi=PR[(d    )*17+bb]+em0;
      float gf=PR[(32+d )*17+bb]+em1;
      float gg=PR[(64+d )*17+bb]+em2;
      float go=PR[(96+d )*17+bb]+em3;
      float c0=sigf(gf)*c0s+sigf(gi)*tanhf(gg);
      c0s=c0;
      float h=sigf(go)*tanhf(c0);
      sh_pub[d*16+bb]=(f16)h;
    }
    __syncthreads();
    if(tid<128){
      int ks=tid>>4, b2=tid&15;
      U64H4 pk;
      #pragma unroll
      for(int i=0;i<4;i++) pk.h[i]=sh_pub[(ks*4+i)*16+b2];
      ast64(&GX0[g*4096+pn*2048+((4*r+(ks>>1))*16+b2)*2+(ks&1)], pk.u);
    }
    PUBF(3*tt+5);      // alpha(tt+1)

    WAITG(3*tt+5);     // exposed hop (no covering work left)

    // B(tt+1) p2: stage h0(tt+1) (also serves next cover1), MFMA, nonlinearity
    {
      u64 s0=ald64(&GX0[g*4096+pn*2048+tid      ]);
      u64 s1=ald64(&GX0[g*4096+pn*2048+tid+512  ]);
      u64 s2=ald64(&GX0[g*4096+pn*2048+tid+1024 ]);
      u64 s3=ald64(&GX0[g*4096+pn*2048+tid+1536 ]);
      HB[tid]=s0; HB[tid+512]=s1; HB[tid+1024]=s2; HB[tid+1536]=s3;
    }
    __syncthreads();
    #pragma unroll
    for(int c=0;c<16;c++){
      f16x8 bfr=HBv[(c*4+q4)*16+lm];
      accB=__builtin_amdgcn_mfma_f32_16x16x32_f16(fb[c],bfr,accB,0,0,0);
    }
    #pragma unroll
    for(int reg=0;reg<4;reg++) PR[(wv*16+q4*4+reg)*17+lm]=accB[reg];
    __syncthreads();
    {
      float gi=PR[(d    )*17+bb]+sh_b1[d];
      float gf=PR[(32+d )*17+bb]+sh_b1[32+d];
      float gg=PR[(64+d )*17+bb]+sh_b1[64+d];
      float go=PR[(96+d )*17+bb]+sh_b1[96+d];
      float c1=sigf(gf)*c1s+sigf(gi)*tanhf(gg);
      c1s=c1;
      float h=sigf(go)*tanhf(c1);
      sh_pub[d*16+bb]=(f16)h;
    }
    __syncthreads();
    if(tid<128){
      int ks=tid>>4, b2=tid&15;
      U64H4 pk;
      #pragma unroll
      for(int i=0;i<4;i++) pk.h[i]=sh_pub[(ks*4+i)*16+b2];
      ast64(&GX1[g*4096+pn*2048+((4*r+(ks>>1))*16+b2)*2+(ks&1)], pk.u);
    }
    PUBF(3*tt+6);      // beta(tt+1)
  }
#undef WAITG
#undef PUBF
}

// ---------------- final output GEMM (f32 out) ----------------
__global__ void __launch_bounds__(256) k_out(const bf16* __restrict__ cat,
                                             const float* __restrict__ Wc,
                                             const float* __restrict__ bc,
                                             float* __restrict__ outp){
  int t0=blockIdx.x*64, v0=blockIdx.y*64, b=blockIdx.z;
  __shared__ float As[64][33];
  __shared__ float Bs[32][65];
  int tid=threadIdx.x;
  int ti=tid>>4, vi=tid&15;
  float acc[4][4]={};
  for(int k0=0;k0<576;k0+=32){
    for(int i=tid;i<64*32;i+=256){
      int rr=i>>5,k=i&31;
      As[rr][k]=b2f(cat[(b*512+t0+rr)*576+k0+k]);
    }
    for(int i=tid;i<64*32;i+=256){
      int v=i>>5,k=i&31;
      Bs[k][v]=Wc[(v0+v)*576+k0+k];
    }
    __syncthreads();
    #pragma unroll 8
    for(int kk=0;kk<32;kk++){
      float av[4],bv[4];
      #pragma unroll
      for(int x=0;x<4;x++) av[x]=As[ti*4+x][kk];
      #pragma unroll
      for(int y=0;y<4;y++) bv[y]=Bs[kk][vi*4+y];
      #pragma unroll
      for(int x=0;x<4;x++)
        #pragma unroll
        for(int y=0;y<4;y++) acc[x][y]+=av[x]*bv[y];
    }
    __syncthreads();
  }
  #pragma unroll
  for(int y=0;y<4;y++){
    int v=v0+vi*4+y;
    float bcv=bc[v];
    #pragma unroll
    for(int x=0;x<4;x++){
      int tt=t0+ti*4+x;
      outp[(b*256+v)*512+tt]=acc[x][y]+bcv;
    }
  }
}

extern "C" void kernel_launch(void* const* d_in, const int* in_sizes, int n_in,
                              void* d_out, int out_size, void* d_ws, size_t ws_size,
                              hipStream_t stream) {
  const int*  tokens = (const int*) d_in[0];
  const void* emb    = d_in[1];
  const void* Wi0    = d_in[2];
  const void* Wh0    = d_in[3];
  const void* b0     = d_in[4];
  const void* Wi1    = d_in[5];
  const void* Wh1    = d_in[6];
  const void* b1     = d_in[7];
  const void* W_if   = d_in[8];
  const void* b_if   = d_in[9];
  const void* W_out  = d_in[10];
  const void* b_out  = d_in[11];
  const void* W_fc   = d_in[12];
  const void* b_fc   = d_in[13];

  static const int expect[14] = {64*512, 256*512, 2048*576, 2048*512, 2048,
                                 2048*512, 2048*512, 2048, 135*512, 135,
                                 512*576, 512, 256*512, 256};
  bool ok = (n_in == 14);
  if(ok) for(int i=0;i<14;i++) if(in_sizes[i]!=expect[i]) ok=false;

  int*      flags = (int*)d_ws;                   // [0]=dtype flag
  float*    embW  = (float*)d_ws + 64;            // 2048*256
  ushort_t* PA    = (ushort_t*)(embW + 524288);   // region 1310720 f16 (uses 1179648; FL at +1179648)
  ushort_t* PB    = PA + 1310720;                 // 2097152 f16
  float*    W_ifT = (float*)(PB + 2097152);       // 69632
  float*    b_ifF = W_ifT + 69632;                // 160
  float*    Wc    = b_ifF + 160;                  // 147456
  float*    bc    = Wc + 147456;                  // 256
  u64*      GX0   = (u64*)(bc + 256);             // 16384 u64 = [4 grp][2 ph][2048]
  u64*      GX1   = GX0 + 16384;                  // 16384 u64
  u64*      GXL   = GX1 + 16384;                  // 2048 u64  = [4 grp][2 ph][256]
  bf16*     cat   = (bf16*)(GXL + 2048);          // 64*512*576
  unsigned* FL    = (unsigned*)(PA + 1179648);    // 64 dwords: 4 groups x 16 flags (64B/group)

  size_t need = 9783168ull + 278528ull + 37748736ull;   // = 47,810,432 B
  if(!ok || ws_size < need){
    hipMemsetAsync(d_out, 0, (size_t)out_size*4, stream);
    return;
  }

  k_detect<<<dim3(1), dim3(256), 0, stream>>>(emb, flags);
  k_embW<<<dim3(2048), dim3(256), 0, stream>>>(emb, Wi0, b0, flags, embW);
  k_wpkA<<<dim3(4608), dim3(256), 0, stream>>>(Wh0, Wi0, flags, PA);
  k_wpkB<<<dim3(8192), dim3(256), 0, stream>>>(Wi1, Wh1, flags, PB);
  k_wifT<<<dim3((135*512+255)/256), dim3(256), 0, stream>>>(W_if, b_if, flags, W_ifT, b_ifF, FL);
  k_wc  <<<dim3(576),  dim3(256), 0, stream>>>(W_fc, W_out, b_out, b_fc, flags, Wc, bc);

  void* kargs[] = {
    (void*)&tokens, (void*)&b1, (void*)&flags,
    (void*)&embW, (void*)&PA, (void*)&PB,
    (void*)&W_ifT, (void*)&b_ifF,
    (void*)&GX0, (void*)&GX1, (void*)&GXL, (void*)&FL,
    (void*)&cat
  };
  hipLaunchCooperativeKernel((const void*)k_dnc3, dim3(64), dim3(512), kargs, 0, stream);

  k_out<<<dim3(8,4,64), dim3(256), 0, stream>>>(cat, Wc, bc, (float*)d_out);
}

// Round 5
// 13967.345 us; speedup vs baseline: 1.3763x; 1.3763x over previous
//
#include <hip/hip_runtime.h>
#include <hip/hip_bf16.h>

typedef __hip_bfloat16 bf16;
typedef _Float16 f16;
typedef _Float16 f16x8 __attribute__((ext_vector_type(8)));
typedef float f32x4 __attribute__((ext_vector_type(4)));
typedef unsigned long long u64;
typedef unsigned short ushort_t;

__device__ __forceinline__ float b2f(bf16 x){ return __bfloat162float(x); }
__device__ __forceinline__ float sigf(float x){ return 1.f/(1.f+expf(-x)); }
__device__ __forceinline__ float splus(float x){ return fmaxf(x,0.f)+log1pf(expf(-fabsf(x))); }
__device__ __forceinline__ float ldf(const void* p, int i, int isf32){
  return isf32 ? ((const float*)p)[i] : __bfloat162float(((const bf16*)p)[i]);
}
// agent-scope coherent ops (bypass per-XCD L2). Proven cross-XCD coherent, no fences.
__device__ __forceinline__ void ast64(u64* p, u64 v){ __hip_atomic_store(p, v, __ATOMIC_RELAXED, __HIP_MEMORY_SCOPE_AGENT); }
__device__ __forceinline__ u64 ald64(u64* p){ return __hip_atomic_load(p, __ATOMIC_RELAXED, __HIP_MEMORY_SCOPE_AGENT); }
__device__ __forceinline__ void ast32(unsigned* p, unsigned v){ __hip_atomic_store(p, v, __ATOMIC_RELAXED, __HIP_MEMORY_SCOPE_AGENT); }
__device__ __forceinline__ unsigned ald32(unsigned* p){ return __hip_atomic_load(p, __ATOMIC_RELAXED, __HIP_MEMORY_SCOPE_AGENT); }

union U4H8 { uint4 u; f16x8 h; };
union U64H4 { u64 u; f16 h[4]; };
union H16 { f16 h; ushort_t s; };

// ---------------- dtype detect ----------------
__global__ void k_detect(const void* __restrict__ emb, int* __restrict__ flag){
  __shared__ float mx[256];
  int tid=threadIdx.x;
  float v = fabsf(__bfloat162float(((const bf16*)emb)[tid]));
  mx[tid]=v; __syncthreads();
  for(int s=128;s>0;s>>=1){ if(tid<s) mx[tid]=fmaxf(mx[tid],mx[tid+s]); __syncthreads(); }
  if(tid==0){ flag[0] = (mx[0]>1000.f) ? 1 : 0; flag[1] = 0; }
}

// ---------------- setup ----------------
// embW[row][v] = b0[row] + sum_k emb[v][k]*Wi0[row][k]   (row-major [2048][256])
__global__ void k_embW(const void* __restrict__ emb, const void* __restrict__ Wi0,
                       const void* __restrict__ b0,
                       const int* __restrict__ flags, float* __restrict__ embW){
  int f=flags[0];
  int row = blockIdx.x;
  __shared__ float w[512];
  for(int k=threadIdx.x;k<512;k+=256) w[k]=ldf(Wi0,row*576+k,f);
  __syncthreads();
  int v = threadIdx.x;
  float acc=ldf(b0,row,f);
  #pragma unroll 4
  for(int k=0;k<512;k++) acc += ldf(emb,v*512+k,f)*w[k];
  embW[row*256+v]=acc;
}

// ---- weight prepack (group design) ----
// Block (g,r): r owns hidden dims [32r,32r+32) -> 128 gate rows. Wave w=G*2+h owns
// rows G*512 + r*32 + h*16 + [0,16). A-frag 16x16x32 f16: lane l row (l&15),
// k=(l>>4)*8+j.  PA chunks c=0..17: k<512 Wh0, k>=512 Wi0 lr cols.
__global__ void k_wpkA(const void* __restrict__ Wh0, const void* __restrict__ Wi0,
                       const int* __restrict__ flags, ushort_t* __restrict__ PA){
  int f=flags[0];
  int idx=blockIdx.x*256+threadIdx.x;
  if(idx>=1179648) return;
  int j=idx&7, l=(idx>>3)&63, rest=idx>>9;
  int c=rest%18, t2=rest/18, w=t2&7, r=t2>>3;
  int G=w>>1, hh=w&1, m=l&15, q4=l>>4;
  int row=G*512 + r*32 + hh*16 + m;
  int k=c*32 + q4*8 + j;
  float val = (k<512)? ldf(Wh0,row*512+k,f) : ldf(Wi0,row*576+k,f);
  H16 hx; hx.h=(f16)val; PA[idx]=hx.s;
}
// PB chunks c=0..31: k<512 Wi1 (h0(t)), k>=512 Wh1 (h1(t-1)).
__global__ void k_wpkB(const void* __restrict__ Wi1, const void* __restrict__ Wh1,
                       const int* __restrict__ flags, ushort_t* __restrict__ PB){
  int f=flags[0];
  int idx=blockIdx.x*256+threadIdx.x;
  if(idx>=2097152) return;
  int j=idx&7, l=(idx>>3)&63, rest=idx>>9;
  int c=rest&31, t2=rest>>5, w=t2&7, r=t2>>3;
  int G=w>>1, hh=w&1, m=l&15, q4=l>>4;
  int row=G*512 + r*32 + hh*16 + m;
  int k=c*32 + q4*8 + j;
  float val = (k<512)? ldf(Wi1,row*512+k,f) : ldf(Wh1,row*512+k-512,f);
  H16 hx; hx.h=(f16)val; PB[idx]=hx.s;
}

// W_if prepack into MFMA A-frags: 9 tiles of 16 rows (rows 128..143 zero-padded
// past 135), 16 K-chunks. PW[((tile*16+c)*64+l)*8+j]: row=tile*16+(l&15),
// k=c*32+(l>>4)*8+j. Also zeroes FL (64 dwords) and loads b_ifF.
__global__ void k_wifP(const void* __restrict__ W_if, const void* __restrict__ b_if,
                       const int* __restrict__ flags,
                       ushort_t* __restrict__ PW, float* __restrict__ b_ifF,
                       unsigned* __restrict__ FLz){
  int f=flags[0];
  int idx=blockIdx.x*256+threadIdx.x;
  if(idx<73728){
    int j=idx&7, l=(idx>>3)&63, c=(idx>>9)&15, tile=idx>>13;
    int row=tile*16+(l&15);
    int k=c*32+(l>>4)*8+j;
    float val=(row<135)? ldf(W_if,row*512+k,f) : 0.f;
    H16 hx; hx.h=(f16)val; PW[idx]=hx.s;
  }
  if(idx<64) FLz[idx]=0u;
  if(idx<135) b_ifF[idx]=ldf(b_if,idx,f);
}

__global__ void k_wc(const void* __restrict__ W_fc, const void* __restrict__ W_out,
                     const void* __restrict__ b_out, const void* __restrict__ b_fc,
                     const int* __restrict__ flags,
                     float* __restrict__ Wc, float* __restrict__ bc){
  int f=flags[0];
  int idx=blockIdx.x*256+threadIdx.x;
  int v=idx/576, j=idx-v*576;
  float acc=0.f;
  #pragma unroll 4
  for(int d=0;d<512;d++) acc += ldf(W_fc,v*512+d,f)*ldf(W_out,d*576+j,f);
  Wc[idx]=acc;
  if(j==0){
    float a=ldf(b_fc,v,f);
    for(int d=0;d<512;d++) a += ldf(W_fc,v*512+d,f)*ldf(b_out,d,f);
    bc[v]=a;
  }
}

// ---------------- grouped recurrence, 2-hop schedule with redundant P3 ----------------
// 4 groups x 16 blocks. Block (g,r) owns dims [32r,32r+32) (weights AGPR/VGPR-resident).
// EVERY block runs the full DNC machinery for ALL 16 batches of its group
// (bit-identical across blocks -> no lr exchange, gamma hop eliminated).
// Interface GEMM xi = W_if(135x512) @ h1 via 144 MFMAs/block using the h1 tile
// already staged for the LSTM (clip(+-20) is a no-op: |h1|<1).
// Flags: FL[g*16+r] monotone: init=1, alpha(t)=2t+2, beta(t)=2t+3.
// Iteration tt: cover1(A(tt+1)p1 on LDS h0(tt)) -> WAIT beta(tt) -> stage h1(tt)
// -> P3-16x(tt) -> A p2 (local lr frags) -> PUB alpha(tt+1) -> cover2(B p1 on
// LDS h1(tt), cat stores) -> WAIT alpha(tt+1) -> stage h0(tt+1) -> B p2 -> PUB beta.
// Overwrite safety (double-buffered GX0/GX1 by t&1) re-verified via flag chain.
__attribute__((amdgpu_waves_per_eu(2,2)))
__global__ void __launch_bounds__(512) k_dnc3(
    const int* __restrict__ tokens, const void* __restrict__ b1, const int* __restrict__ flags,
    const float* __restrict__ embW, const ushort_t* __restrict__ PA, const ushort_t* __restrict__ PB,
    const ushort_t* __restrict__ PW, const float* __restrict__ b_ifF,
    u64* GX0, u64* GX1, unsigned* FL,
    bf16* __restrict__ cat)
{
  const int bid = blockIdx.x;
  const int g   = bid>>4, r = bid&15;
  const int tid = threadIdx.x;
  const int wv  = tid>>6, l = tid&63;
  const int lm  = l&15,  q4 = l>>4;
  const int d   = tid>>4, bb = tid&15;     // nonlinearity mapping (dim, batch)
  const int mb  = tid>>5, mu = tid&31;     // machinery mapping (batch, slot)
  const int f32i = flags[0];

  __shared__ __align__(16) u64 HB[4352];   // [0..2047] h0 | [2048..4095] h1 | [4096..4351] lr frags
  __shared__ float PR[128*17];
  __shared__ f16  sh_pub[512];
  __shared__ float sh_b1[128];
  __shared__ float b_ifL[144];
  __shared__ float xis2[16*149];
  __shared__ float s_mem[1280], s_mem2[1280], s_link[400], s_link2[400];
  __shared__ float s_prec[80], s_prec2[80], s_rwp[320], s_rw[320];
  __shared__ float s_wwp[80], s_ww[80], s_usage[80], s_wl[80];
  __shared__ float s_rl[320], s_fwd[320], s_bwd[320], s_wsum[16];
  __shared__ float rvbuf[1024];

#define WAITG(TGT) do{ if(tid<16){ unsigned _tg=(unsigned)(TGT); int _wd=0; \
    while(ald32(&FL[g*16+tid]) < _tg && _wd<50000000){ __builtin_amdgcn_s_sleep(1); _wd++; } } \
  __syncthreads(); }while(0)
#define PUBF(VAL) do{ __syncthreads(); \
  if(tid==0) ast32(&FL[g*16+r],(unsigned)(VAL)); }while(0)
#define XI(i) xis2[mb*149+(i)]

  // resident weight fragments (~200 regs, AGPR/VGPR unified)
  f16x8 fa[18], fb[32];
  {
    const uint4* PAv=(const uint4*)PA;
    const uint4* PBv=(const uint4*)PB;
    #pragma unroll
    for(int c=0;c<18;c++){ U4H8 t4; t4.u = PAv[((r*8+wv)*18+c)*64 + l]; fa[c]=t4.h; }
    #pragma unroll
    for(int c=0;c<32;c++){ U4H8 t4; t4.u = PBv[((r*8+wv)*32+c)*64 + l]; fb[c]=t4.h; }
    #pragma unroll
    for(int c=0;c<18;c++) asm volatile("" :: "v"(fa[c]));
    #pragma unroll
    for(int c=0;c<32;c++) asm volatile("" :: "v"(fb[c]));
  }
  if(tid<128) sh_b1[tid]=ldf(b1,(tid>>5)*512 + r*32 + (tid&31), f32i);
  if(tid<144) b_ifL[tid]=(tid<135)? b_ifF[tid] : 0.f;
  for(int i=tid;i<1280;i+=512) s_mem[i]=0.f;
  for(int i=tid;i<400;i+=512) s_link[i]=0.f;
  for(int i=tid;i<320;i+=512) s_rwp[i]=0.f;
  if(tid<80){ s_prec[tid]=0.f; s_wwp[tid]=0.f; s_usage[tid]=0.f; }
  float c0s=0.f, c1s=0.f;

  const f16x8* HBv=(const f16x8*)HB;
  const uint4* PWv=(const uint4*)PW;

  // ---- prologue: t=0 ----
  {
    int tok0=tokens[(g*16+bb)*512];
    int base0=(r*32+d)*256+tok0;
    float e0=embW[base0], e2=embW[262144+base0], e3=embW[393216+base0];
    c0s = sigf(e0)*tanhf(e2);
    float h0v = sigf(e3)*tanhf(c0s);
    sh_pub[d*16+bb]=(f16)h0v;
  }
  __syncthreads();
  if(tid<128){
    int ks=tid>>4, b2=tid&15;
    U64H4 pk;
    #pragma unroll
    for(int i=0;i<4;i++) pk.h[i]=sh_pub[(ks*4+i)*16+b2];
    ast64(&GX0[g*4096+((4*r+(ks>>1))*16+b2)*2+(ks&1)], pk.u);
  }
  PUBF(2u);            // alpha(0)
  WAITG(2u);
  {
    u64 s0=ald64(&GX0[g*4096+tid      ]);
    u64 s1=ald64(&GX0[g*4096+tid+512  ]);
    u64 s2=ald64(&GX0[g*4096+tid+1024 ]);
    u64 s3=ald64(&GX0[g*4096+tid+1536 ]);
    HB[tid]=s0; HB[tid+512]=s1; HB[tid+1024]=s2; HB[tid+1536]=s3;
  }
  __syncthreads();
  {
    f32x4 accB=(f32x4){0.f,0.f,0.f,0.f};
    #pragma unroll
    for(int c=0;c<16;c++){
      f16x8 bfr=HBv[(c*4+q4)*16+lm];
      accB=__builtin_amdgcn_mfma_f32_16x16x32_f16(fb[c],bfr,accB,0,0,0);
    }
    #pragma unroll
    for(int reg=0;reg<4;reg++) PR[(wv*16+q4*4+reg)*17+lm]=accB[reg];
  }
  __syncthreads();
  {
    float gi=PR[(d    )*17+bb]+sh_b1[d];
    float gg=PR[(64+d )*17+bb]+sh_b1[64+d];
    float go=PR[(96+d )*17+bb]+sh_b1[96+d];
    c1s = sigf(gi)*tanhf(gg);
    float h=sigf(go)*tanhf(c1s);
    sh_pub[d*16+bb]=(f16)h;
  }
  __syncthreads();
  if(tid<128){
    int ks=tid>>4, b2=tid&15;
    U64H4 pk;
    #pragma unroll
    for(int i=0;i<4;i++) pk.h[i]=sh_pub[(ks*4+i)*16+b2];
    ast64(&GX1[g*4096+((4*r+(ks>>1))*16+b2)*2+(ks&1)], pk.u);
  }
  PUBF(3u);            // beta(0)

  // ---- main loop ----
  for(int tt=0;tt<512;tt++){
    const int p=tt&1, pn=p^1;

    // cover1: A(tt+1) p1 on h0(tt) resident in HB[0..2047]
    f32x4 accA=(f32x4){0.f,0.f,0.f,0.f};
    #pragma unroll
    for(int c=0;c<16;c++){
      f16x8 bfr=HBv[(c*4+q4)*16+lm];
      accA=__builtin_amdgcn_mfma_f32_16x16x32_f16(fa[c],bfr,accA,0,0,0);
    }
    float em0,em1,em2,em3;
    {
      int tn=(tt<511)?tt+1:511;
      int tok=tokens[(g*16+bb)*512+tn];
      int base=(r*32+d)*256+tok;
      em0=embW[base]; em1=embW[131072+base]; em2=embW[262144+base]; em3=embW[393216+base];
    }

    WAITG(2*tt+3);     // beta(tt)

    // stage h1(tt) -> HB[2048..4095]
    {
      u64 s0=ald64(&GX1[g*4096+p*2048+tid      ]);
      u64 s1=ald64(&GX1[g*4096+p*2048+tid+512  ]);
      u64 s2=ald64(&GX1[g*4096+p*2048+tid+1024 ]);
      u64 s3=ald64(&GX1[g*4096+p*2048+tid+1536 ]);
      HB[2048+tid]=s0; HB[2048+tid+512]=s1; HB[2048+tid+1024]=s2; HB[2048+tid+1536]=s3;
    }
    __syncthreads();

    // ====== P3-16x: xi = W_if @ h1 for all 16 batches via MFMA ======
    {
      f32x4 xa=(f32x4){0.f,0.f,0.f,0.f};
      #pragma unroll
      for(int hh=0;hh<4;hh++){
        uint4 w4[4];
        #pragma unroll
        for(int cc=0;cc<4;cc++) w4[cc]=PWv[(wv*16 + hh*4+cc)*64 + l];
        #pragma unroll
        for(int cc=0;cc<4;cc++){
          U4H8 t4; t4.u=w4[cc];
          f16x8 bfr=HBv[1024+((hh*4+cc)*4+q4)*16+lm];
          xa=__builtin_amdgcn_mfma_f32_16x16x32_f16(t4.h,bfr,xa,0,0,0);
        }
      }
      #pragma unroll
      for(int reg=0;reg<4;reg++){
        int row=wv*16+q4*4+reg;
        xis2[lm*149+row]=xa[reg]+b_ifL[row];
      }
      if(wv==0){
        f32x4 xb=(f32x4){0.f,0.f,0.f,0.f};
        #pragma unroll
        for(int hh=0;hh<4;hh++){
          uint4 w4[4];
          #pragma unroll
          for(int cc=0;cc<4;cc++) w4[cc]=PWv[(128 + hh*4+cc)*64 + l];
          #pragma unroll
          for(int cc=0;cc<4;cc++){
            U4H8 t4; t4.u=w4[cc];
            f16x8 bfr=HBv[1024+((hh*4+cc)*4+q4)*16+lm];
            xb=__builtin_amdgcn_mfma_f32_16x16x32_f16(t4.h,bfr,xb,0,0,0);
          }
        }
        #pragma unroll
        for(int reg=0;reg<4;reg++){
          int row=128+q4*4+reg;
          xis2[lm*149+row]=xb[reg]+b_ifL[row];
        }
      }
    }
    __syncthreads();

    // M1: usage/psi + write-key cosine (5 slots/batch)
    if(mu<5){
      int m=mu;
      float u=s_usage[mb*5+m]+(1.f-s_usage[mb*5+m])*s_wwp[mb*5+m];
      float psi=1.f;
      #pragma unroll
      for(int rr=0;rr<4;rr++) psi *= 1.f - sigf(XI(117+rr))*s_rwp[mb*20+rr*5+m];
      u*=psi; s_usage[mb*5+m]=u;
      float nm=0.f,dt=0.f,nk=0.f;
      #pragma unroll
      for(int w=0;w<16;w++){
        float mv=s_mem[mb*80+m*16+w], kv=tanhf(XI(68+w));
        nm+=mv*mv; dt+=mv*kv; nk+=kv*kv;
      }
      float sim=dt/((sqrtf(nm)+1e-6f)*(sqrtf(nk)+1e-6f));
      s_wl[mb*5+m]=sim*splus(XI(84));
    }
    __syncthreads();
    // M2: write softmax + allocation (1 slot/batch)
    if(mu==0){
      float mx=-1e30f;
      for(int m=0;m<5;m++) mx=fmaxf(mx,s_wl[mb*5+m]);
      float e[5]; float s=0.f;
      for(int m=0;m<5;m++){ e[m]=expf(s_wl[mb*5+m]-mx); s+=e[m]; }
      float u[5]; int id[5];
      for(int m=0;m<5;m++){ u[m]=1e-6f+(1.f-1e-6f)*s_usage[mb*5+m]; id[m]=m; }
      for(int i=1;i<5;i++){
        float uv=u[i]; int iv=id[i]; int j=i-1;
        while(j>=0&&u[j]>uv){u[j+1]=u[j];id[j+1]=id[j];j--;}
        u[j+1]=uv; id[j+1]=iv;
      }
      float alm[5]; float prod=1.f;
      for(int i=0;i<5;i++){ alm[id[i]]=(1.f-u[i])*prod; prod*=u[i]; }
      float ag=sigf(XI(121)), wgg=sigf(XI(122));
      float wsum=0.f;
      for(int m=0;m<5;m++){
        float wcw=e[m]/s;
        float w_=wgg*(ag*alm[m]+(1.f-ag)*wcw);
        s_ww[mb*5+m]=w_; wsum+=w_;
      }
      s_wsum[mb]=wsum;
    }
    __syncthreads();
    // M3: mem2 (80), link2 (25), prec2 (5)
    for(int k=mu;k<80;k+=32){
      int m=k>>4,w=k&15;
      float er=sigf(XI(85+w)), wv2=tanhf(XI(101+w));
      float w_=s_ww[mb*5+m];
      s_mem2[mb*80+k]=s_mem[mb*80+k]*(1.f-w_*er)+w_*wv2;
    }
    if(mu<25){
      int i=mu/5, j=mu-5*i;
      s_link2[mb*25+mu]=(i==j)?0.f:((1.f-s_ww[mb*5+i]-s_ww[mb*5+j])*s_link[mb*25+mu]+s_ww[mb*5+i]*s_prec[mb*5+j]);
    } else if(mu<30){
      int j=mu-25;
      s_prec2[mb*5+j]=(1.f-s_wsum[mb])*s_prec[mb*5+j]+s_ww[mb*5+j];
    }
    __syncthreads();
    // M4: read cosine + fwd + bwd (20 slots/batch, 3 tasks per slot)
    if(mu<20){
      int rr=mu/5, m=mu-5*rr;
      float nm=0.f,dt=0.f,nk=0.f;
      #pragma unroll
      for(int w=0;w<16;w++){
        float mv=s_mem2[mb*80+m*16+w], kv=tanhf(XI(rr*16+w));
        nm+=mv*mv; dt+=mv*kv; nk+=kv*kv;
      }
      float sim=dt/((sqrtf(nm)+1e-6f)*(sqrtf(nk)+1e-6f));
      s_rl[mb*20+mu]=sim*splus(XI(64+rr));
      float af=0.f, ab=0.f;
      #pragma unroll
      for(int j=0;j<5;j++) af+=s_link2[mb*25+m*5+j]*s_rwp[mb*20+rr*5+j];
      #pragma unroll
      for(int i=0;i<5;i++) ab+=s_link2[mb*25+i*5+m]*s_rwp[mb*20+rr*5+i];
      s_fwd[mb*20+rr*5+m]=af;
      s_bwd[mb*20+rr*5+m]=ab;
    }
    __syncthreads();
    // M5: read softmax + modes
    if(mu<20){
      int rr=mu/5;
      float mx=-1e30f;
      for(int m=0;m<5;m++) mx=fmaxf(mx,s_rl[mb*20+rr*5+m]);
      float s=0.f;
      for(int m=0;m<5;m++) s+=expf(s_rl[mb*20+rr*5+m]-mx);
      float rcw=expf(s_rl[mb*20+mu]-mx)/s;
      float q0=XI(123+3*rr),q1=XI(124+3*rr),q2=XI(125+3*rr);
      float m3=fmaxf(q0,fmaxf(q1,q2));
      float e0=expf(q0-m3),e1=expf(q1-m3),e2=expf(q2-m3);
      float inv=1.f/(e0+e1+e2);
      s_rw[mb*20+mu]=(e0*s_bwd[mb*20+mu]+e1*s_fwd[mb*20+mu]+e2*rcw)*inv;
    }
    __syncthreads();
    // M6: read vectors (64) + state copies
    for(int k=mu;k<64;k+=32){
      int rr=k>>4,w=k&15;
      float a=0.f;
      #pragma unroll
      for(int m=0;m<5;m++) a+=s_rw[mb*20+rr*5+m]*s_mem2[mb*80+m*16+w];
      rvbuf[mb*64+k]=a;
    }
    for(int k=mu;k<80;k+=32) s_mem[mb*80+k]=s_mem2[mb*80+k];
    if(mu<25) s_link[mb*25+mu]=s_link2[mb*25+mu];
    else if(mu<30) s_prec[mb*5+mu-25]=s_prec2[mb*5+mu-25];
    if(mu<20) s_rwp[mb*20+mu]=s_rw[mb*20+mu];
    if(mu>=27&&mu<32){ int m=mu-27; s_wwp[mb*5+m]=s_ww[mb*5+m]; }
    __syncthreads();

    if(tt==511){
      int cb=((g*16+r)*512+tt)*576;
      if(tid<128){
        int kg=tid>>1, e=tid&1;
        U64H4 pv; pv.u=HB[2048+(kg*16+r)*2+e];
        #pragma unroll
        for(int i=0;i<4;i++){
          float x=(float)pv.h[i];
          cat[cb+kg*8+e*4+i]=__float2bfloat16(fminf(fmaxf(x,-20.f),20.f));
        }
      }
      if(tid<64) cat[cb+512+tid]=__float2bfloat16(rvbuf[r*64+tid]);
      break;
    }

    // build lr B-frags in HB[4096..4351]
    if(tid<256){
      int kg=tid>>5, rem=tid&31, b2=rem>>1, e=rem&1;
      U64H4 pk;
      #pragma unroll
      for(int i=0;i<4;i++) pk.h[i]=(f16)rvbuf[b2*64 + kg*8+e*4+i];
      HB[4096+(kg*16+b2)*2+e]=pk.u;
    }
    __syncthreads();
    // A(tt+1) p2: lr chunks + nonlinearity
    #pragma unroll
    for(int c2=0;c2<2;c2++){
      f16x8 bfr=HBv[2048+(c2*4+q4)*16+lm];
      accA=__builtin_amdgcn_mfma_f32_16x16x32_f16(fa[16+c2],bfr,accA,0,0,0);
    }
    #pragma unroll
    for(int reg=0;reg<4;reg++) PR[(wv*16+q4*4+reg)*17+lm]=accA[reg];
    __syncthreads();
    {
      float gi=PR[(d    )*17+bb]+em0;
      float gf=PR[(32+d )*17+bb]+em1;
      float gg=PR[(64+d )*17+bb]+em2;
      float go=PR[(96+d )*17+bb]+em3;
      float c0=sigf(gf)*c0s+sigf(gi)*tanhf(gg);
      c0s=c0;
      float h=sigf(go)*tanhf(c0);
      sh_pub[d*16+bb]=(f16)h;
    }
    __syncthreads();
    if(tid<128){
      int ks=tid>>4, b2=tid&15;
      U64H4 pk;
      #pragma unroll
      for(int i=0;i<4;i++) pk.h[i]=sh_pub[(ks*4+i)*16+b2];
      ast64(&GX0[g*4096+pn*2048+((4*r+(ks>>1))*16+b2)*2+(ks&1)], pk.u);
    }
    PUBF(2*tt+4);      // alpha(tt+1)

    // cover2: B(tt+1) p1 on h1(tt) already in HB; cat stores for tt
    f32x4 accB=(f32x4){0.f,0.f,0.f,0.f};
    #pragma unroll
    for(int c=16;c<32;c++){
      f16x8 bfr=HBv[1024+((c-16)*4+q4)*16+lm];
      accB=__builtin_amdgcn_mfma_f32_16x16x32_f16(fb[c],bfr,accB,0,0,0);
    }
    {
      int cb=((g*16+r)*512+tt)*576;
      if(tid<128){
        int kg=tid>>1, e=tid&1;
        U64H4 pv; pv.u=HB[2048+(kg*16+r)*2+e];
        #pragma unroll
        for(int i=0;i<4;i++){
          float x=(float)pv.h[i];
          cat[cb+kg*8+e*4+i]=__float2bfloat16(fminf(fmaxf(x,-20.f),20.f));
        }
      }
      if(tid<64) cat[cb+512+tid]=__float2bfloat16(rvbuf[r*64+tid]);
    }

    WAITG(2*tt+4);     // alpha(tt+1)

    // B(tt+1) p2: stage h0(tt+1), MFMA, nonlinearity
    {
      u64 s0=ald64(&GX0[g*4096+pn*2048+tid      ]);
      u64 s1=ald64(&GX0[g*4096+pn*2048+tid+512  ]);
      u64 s2=ald64(&GX0[g*4096+pn*2048+tid+1024 ]);
      u64 s3=ald64(&GX0[g*4096+pn*2048+tid+1536 ]);
      HB[tid]=s0; HB[tid+512]=s1; HB[tid+1024]=s2; HB[tid+1536]=s3;
    }
    __syncthreads();
    #pragma unroll
    for(int c=0;c<16;c++){
      f16x8 bfr=HBv[(c*4+q4)*16+lm];
      accB=__builtin_amdgcn_mfma_f32_16x16x32_f16(fb[c],bfr,accB,0,0,0);
    }
    #pragma unroll
    for(int reg=0;reg<4;reg++) PR[(wv*16+q4*4+reg)*17+lm]=accB[reg];
    __syncthreads();
    {
      float gi=PR[(d    )*17+bb]+sh_b1[d];
      float gf=PR[(32+d )*17+bb]+sh_b1[32+d];
      float gg=PR[(64+d )*17+bb]+sh_b1[64+d];
      float go=PR[(96+d )*17+bb]+sh_b1[96+d];
      float c1=sigf(gf)*c1s+sigf(gi)*tanhf(gg);
      c1s=c1;
      float h=sigf(go)*tanhf(c1);
      sh_pub[d*16+bb]=(f16)h;
    }
    __syncthreads();
    if(tid<128){
      int ks=tid>>4, b2=tid&15;
      U64H4 pk;
      #pragma unroll
      for(int i=0;i<4;i++) pk.h[i]=sh_pub[(ks*4+i)*16+b2];
      ast64(&GX1[g*4096+pn*2048+((4*r+(ks>>1))*16+b2)*2+(ks&1)], pk.u);
    }
    PUBF(2*tt+5);      // beta(tt+1)
  }
#undef WAITG
#undef PUBF
#undef XI
}

// ---------------- final output GEMM (f32 out) ----------------
__global__ void __launch_bounds__(256) k_out(const bf16* __restrict__ cat,
                                             const float* __restrict__ Wc,
                                             const float* __restrict__ bc,
                                             float* __restrict__ outp){
  int t0=blockIdx.x*64, v0=blockIdx.y*64, b=blockIdx.z;
  __shared__ float As[64][33];
  __shared__ float Bs[32][65];
  int tid=threadIdx.x;
  int ti=tid>>4, vi=tid&15;
  float acc[4][4]={};
  for(int k0=0;k0<576;k0+=32){
    for(int i=tid;i<64*32;i+=256){
      int rr=i>>5,k=i&31;
      As[rr][k]=b2f(cat[(b*512+t0+rr)*576+k0+k]);
    }
    for(int i=tid;i<64*32;i+=256){
      int v=i>>5,k=i&31;
      Bs[k][v]=Wc[(v0+v)*576+k0+k];
    }
    __syncthreads();
    #pragma unroll 8
    for(int kk=0;kk<32;kk++){
      float av[4],bv[4];
      #pragma unroll
      for(int x=0;x<4;x++) av[x]=As[ti*4+x][kk];
      #pragma unroll
      for(int y=0;y<4;y++) bv[y]=Bs[kk][vi*4+y];
      #pragma unroll
      for(int x=0;x<4;x++)
        #pragma unroll
        for(int y=0;y<4;y++) acc[x][y]+=av[x]*bv[y];
    }
    __syncthreads();
  }
  #pragma unroll
  for(int y=0;y<4;y++){
    int v=v0+vi*4+y;
    float bcv=bc[v];
    #pragma unroll
    for(int x=0;x<4;x++){
      int tt=t0+ti*4+x;
      outp[(b*256+v)*512+tt]=acc[x][y]+bcv;
    }
  }
}

extern "C" void kernel_launch(void* const* d_in, const int* in_sizes, int n_in,
                              void* d_out, int out_size, void* d_ws, size_t ws_size,
                              hipStream_t stream) {
  const int*  tokens = (const int*) d_in[0];
  const void* emb    = d_in[1];
  const void* Wi0    = d_in[2];
  const void* Wh0    = d_in[3];
  const void* b0     = d_in[4];
  const void* Wi1    = d_in[5];
  const void* Wh1    = d_in[6];
  const void* b1     = d_in[7];
  const void* W_if   = d_in[8];
  const void* b_if   = d_in[9];
  const void* W_out  = d_in[10];
  const void* b_out  = d_in[11];
  const void* W_fc   = d_in[12];
  const void* b_fc   = d_in[13];

  static const int expect[14] = {64*512, 256*512, 2048*576, 2048*512, 2048,
                                 2048*512, 2048*512, 2048, 135*512, 135,
                                 512*576, 512, 256*512, 256};
  bool ok = (n_in == 14);
  if(ok) for(int i=0;i<14;i++) if(in_sizes[i]!=expect[i]) ok=false;

  int*      flags = (int*)d_ws;                   // [0]=dtype flag
  float*    embW  = (float*)d_ws + 64;            // 2048*256
  ushort_t* PA    = (ushort_t*)(embW + 524288);   // region 1310720 f16 (uses 1179648; FL at +1179648)
  ushort_t* PB    = PA + 1310720;                 // 2097152 f16
  float*    Wreg  = (float*)(PB + 2097152);       // 69632 f32 region: PW (73728 f16 = 147456B) lives here
  float*    b_ifF = Wreg + 69632;                 // 160
  float*    Wc    = b_ifF + 160;                  // 147456
  float*    bc    = Wc + 147456;                  // 256
  u64*      GX0   = (u64*)(bc + 256);             // 16384 u64 = [4 grp][2 ph][2048]
  u64*      GX1   = GX0 + 16384;                  // 16384 u64
  u64*      GXL   = GX1 + 16384;                  // 2048 u64 (unused, kept for layout)
  bf16*     cat   = (bf16*)(GXL + 2048);          // 64*512*576
  unsigned* FL    = (unsigned*)(PA + 1179648);    // 64 dwords: 4 groups x 16 flags
  ushort_t* PW    = (ushort_t*)Wreg;              // 73728 f16

  size_t need = 9783168ull + 278528ull + 37748736ull;   // = 47,810,432 B
  if(!ok || ws_size < need){
    hipMemsetAsync(d_out, 0, (size_t)out_size*4, stream);
    return;
  }

  k_detect<<<dim3(1), dim3(256), 0, stream>>>(emb, flags);
  k_embW<<<dim3(2048), dim3(256), 0, stream>>>(emb, Wi0, b0, flags, embW);
  k_wpkA<<<dim3(4608), dim3(256), 0, stream>>>(Wh0, Wi0, flags, PA);
  k_wpkB<<<dim3(8192), dim3(256), 0, stream>>>(Wi1, Wh1, flags, PB);
  k_wifP<<<dim3(288), dim3(256), 0, stream>>>(W_if, b_if, flags, PW, b_ifF, FL);
  k_wc  <<<dim3(576),  dim3(256), 0, stream>>>(W_fc, W_out, b_out, b_fc, flags, Wc, bc);

  void* kargs[] = {
    (void*)&tokens, (void*)&b1, (void*)&flags,
    (void*)&embW, (void*)&PA, (void*)&PB,
    (void*)&PW, (void*)&b_ifF,
    (void*)&GX0, (void*)&GX1, (void*)&FL,
    (void*)&cat
  };
  hipLaunchCooperativeKernel((const void*)k_dnc3, dim3(64), dim3(512), kargs, 0, stream);

  k_out<<<dim3(8,4,64), dim3(256), 0, stream>>>(cat, Wc, bc, (float*)d_out);
}